// Round 11
// baseline (1626.573 us; speedup 1.0000x reference)
//
#include <hip/hip_runtime.h>
#include <stdint.h>

// ---------------------------------------------------------------------------
// LSTMSupertaggingModel: segment-mean-pool -> BiLSTM(H=384) -> Linear(C=425)
// B=64, S=512, D=768, W=256, H=384, C=425
//
// V17 = V16 with ONE variable changed: ADAPTIVE PRE-SLEEP before the mailbox
// spin (per-wave integrator: pre-sleep skipU x s_sleep(8) (~512cy/unit);
// after the spin, polls P>2 -> skipU += P-2, P<=1 -> skipU-- ; cap 16).
//  - V16 post-mortem: split-phase spin NULL -> loads were already batched;
//    per-round ~1 RT. Ledger gap (~3000 vs 6600 cy/step) attributed to
//    SELF-INFLICTED IC CONGESTION: ~6 wasted 24KB poll rounds/wg/step
//    ~= 2.7 TB/s of useless IC reads contending with the publish path.
//    Controller cuts poll traffic ~3x; cannot extend the period (negative
//    feedback, bounded sleep, spin unchanged -> correctness untouched).
//  - V15 lesson: IC atomic-pipeline OP COUNT is the contended currency
//    (64 u16 -> 16 u64 epilogue stores = -278us, FETCH unchanged).
//  - V14 lesson: CU co-residency irrelevant; 84KB LDS kept (private CUs).
//  - V13 structure: fused recur+xp-GEMM (gemm rides free), rows [s*64+b],
//    gcnt gating, both-ends priority, V8-exact mailbox, ldxp prefetch.
//  - exchange-latency line CLOSED (V9-V12); merged prep kernel kept (V16).
// ---------------------------------------------------------------------------

typedef __attribute__((ext_vector_type(8))) short short8;
typedef __attribute__((ext_vector_type(4))) float f32x4;

static constexpr int Bn = 64, Sn = 512, Dn = 768, Wn = 256, Hn = 384, Cn = 425;
static constexpr int G4H = 4 * Hn;          // 1536
static constexpr int NBT = 4;               // batch tiles of 16
static constexpr int NCK = 6;               // h-chunks of 64 rows per dir
static constexpr int NRWG = 2 * NBT * NCK;  // 48 recur wgs

__device__ __forceinline__ unsigned short f2bf(float f) {
  unsigned int u = __float_as_uint(f);
  u += 0x7FFFu + ((u >> 16) & 1u);          // round-to-nearest-even
  return (unsigned short)(u >> 16);
}
__device__ __forceinline__ float bf2f(unsigned short h) {
  return __uint_as_float(((unsigned int)h) << 16);
}
__device__ __forceinline__ float sigm(float x)  { return 1.f / (1.f + __expf(-x)); }
__device__ __forceinline__ float tanhft(float x){ return 1.f - 2.f / (__expf(2.f * x) + 1.f); }

// async global->LDS, 16B per lane; LDS dest = wave-uniform base + lane*16
#define GLL16(gp, lp) __builtin_amdgcn_global_load_lds( \
  (const __attribute__((address_space(1))) unsigned int*)(gp), \
  (__attribute__((address_space(3))) unsigned int*)(lp), 16, 0, 0)

// ---------------------------------------------------------------------------
// merged prep: [0,ZB) zero htag+gcnt | [ZB,ZB+64) scan | [ZB+64,..) cast
static constexpr int COMMW = 2 * 2 * 64 * 384 + 32;   // htag + gcnt words
static constexpr int ZB = (COMMW + 255) / 256;        // 385 blocks
static constexpr int CASTN = 3072 * 768 + 2 * 1536 * 384 + Cn * 768 + 3072;
static constexpr int CB = (CASTN + 255) / 256;

__global__ void prep_kernel(unsigned int* __restrict__ comm,
                            const int* __restrict__ counts, int* __restrict__ starts,
                            const float* __restrict__ Wih_f, const float* __restrict__ Wih_b,
                            const float* __restrict__ Whh_f, const float* __restrict__ Whh_b,
                            const float* __restrict__ Wlin,
                            const float* __restrict__ bih_f, const float* __restrict__ bhh_f,
                            const float* __restrict__ bih_b, const float* __restrict__ bhh_b,
                            unsigned short* __restrict__ wih, unsigned short* __restrict__ whh,
                            unsigned short* __restrict__ wlin, float* __restrict__ biasc) {
  int bid = blockIdx.x;
  if (bid < ZB) {                           // zero comm (UC/atomic path)
    int i = bid * 256 + threadIdx.x;
    if (i < COMMW)
      __hip_atomic_store(&comm[i], 0u, __ATOMIC_RELAXED, __HIP_MEMORY_SCOPE_AGENT);
    return;
  }
  if (bid < ZB + 64) {                      // per-sentence exclusive scan
    int b = bid - ZB, j = threadIdx.x;
    __shared__ int sm[256];
    int c = counts[b * Wn + j];
    sm[j] = c;
    __syncthreads();
    for (int off = 1; off < 256; off <<= 1) {
      int v = (j >= off) ? sm[j - off] : 0;
      __syncthreads();
      sm[j] += v;
      __syncthreads();
    }
    starts[b * Wn + j] = sm[j] - c;
    return;
  }
  int i = (bid - ZB - 64) * 256 + threadIdx.x;
  const int T0 = 3072 * 768;
  const int T1 = 2 * 1536 * 384;
  const int T2 = Cn * 768;
  const int T3 = 3072;
  if (i < T0) {
    int n = i / 768, k = i - n * 768;
    float v = (n < 1536) ? Wih_f[n * 768 + k] : Wih_b[(n - 1536) * 768 + k];
    wih[i] = f2bf(v);
  } else if (i < T0 + T1) {
    int j = i - T0;
    float v = (j < 1536 * 384) ? Whh_f[j] : Whh_b[j - 1536 * 384];
    whh[j] = f2bf(v);
  } else if (i < T0 + T1 + T2) {
    int j = i - T0 - T1;
    wlin[j] = f2bf(Wlin[j]);
  } else if (i < T0 + T1 + T2 + T3) {
    int n = i - T0 - T1 - T2;
    biasc[n] = (n < 1536) ? (bih_f[n] + bhh_f[n]) : (bih_b[n - 1536] + bhh_b[n - 1536]);
  }
}

// ---------------------------------------------------------------------------
// ragged segment mean -> f0p rows [s*64+b][768]
__global__ void pool_kernel(const float* __restrict__ f0, const int* __restrict__ counts,
                            const int* __restrict__ starts, unsigned short* __restrict__ f0p) {
  int idx = blockIdx.x * 256 + threadIdx.x;           // B*S*192 exact
  int dc = idx % 192;
  int rest = idx / 192;
  int s = rest & 511, b = rest >> 9;
  const float4* f4 = (const float4*)f0;
  float4 v;
  if (s < Wn) {
    int st = starts[b * Wn + s], cnt = counts[b * Wn + s];
    v = f4[(size_t)(b * Sn + st) * 192 + dc];
    if (cnt == 2) {
      float4 v2 = f4[(size_t)(b * Sn + st + 1) * 192 + dc];
      v.x = (v.x + v2.x) * 0.5f; v.y = (v.y + v2.y) * 0.5f;
      v.z = (v.z + v2.z) * 0.5f; v.w = (v.w + v2.w) * 0.5f;
    }
  } else {
    v = f4[(size_t)(b * Sn + s) * 192 + dc];
  }
  ushort4 o;
  o.x = f2bf(v.x); o.y = f2bf(v.y); o.z = f2bf(v.z); o.w = f2bf(v.w);
  ((ushort4*)f0p)[(size_t)(s * Bn + b) * 192 + dc] = o;
}

// ---------------------------------------------------------------------------
// FUSED: recur (bid<48) + xp GEMM (bid>=48). 84KB LDS -> 1 wg/CU.
// f0h: f0p rows [s*64+b][768]; recur overwrites row (t*64+b) with h_all.
// xp : [2][512][64][1536] bf16, written via full-sector u64 AGENT atomics.
// gcnt[32]: group counters (8 mtiles x 24 ntiles = 192 per group).
// htag: [2][2][64][384] u32 = (tag<<16)|bf16 agent mailbox (V8-exact).
__global__ void __launch_bounds__(256, 1)
fused_kernel(const unsigned short* __restrict__ whh,   // [2][1536][384] bf16
             unsigned short* xp,                        // in/out (both roles)
             unsigned short* f0h,                       // f0p in, h_all out (overlay)
             const unsigned short* __restrict__ wih,    // [3072][768] bf16
             const float* __restrict__ biasc,           // [3072]
             unsigned int* htag,
             unsigned int* gcnt) {
  // 84KB static LDS: 1 wg/CU (CUs private). Epilogue stage fits (33KB).
  __shared__ __align__(16) char smem[86016];
  int bid = blockIdx.x;
  int tid = threadIdx.x, w = tid >> 6, l = tid & 63, lr = l & 15, lq = l >> 4;

  if (bid < NRWG) {
    // ================= recurrence (V8 core + V17 poll-rate control) =======
    int dir = bid / (NBT * NCK);
    int rem = bid % (NBT * NCK);
    int btile = rem / NCK, chunk = rem % NCK;
    int hwb = chunk * 64 + w * 16;
    int pr = tid >> 4, pk = tid & 15;
    unsigned int (*hlds)[16 * 196] = (unsigned int (*)[16 * 196])smem;

    short8 bfr[4][12];
#pragma unroll
    for (int q = 0; q < 4; ++q)
#pragma unroll
      for (int kf = 0; kf < 12; ++kf)
        bfr[q][kf] = *(const short8*)&whh[((size_t)dir * 1536 + q * 384 + hwb + lr) * 384 + kf * 32 + lq * 8];

    // xp readiness gate: group g = t>>4 ready when gcnt[g]==192
    int lastG = -1;
    auto gate = [&](int tt) {
      int g = tt >> 4;
      if (g != lastG) {
        while (__hip_atomic_load(&gcnt[g], __ATOMIC_RELAXED, __HIP_MEMORY_SCOPE_AGENT) < 192u)
          __builtin_amdgcn_s_sleep(4);
        lastG = g;
        asm volatile("" ::: "memory");      // no xp load hoisting above the gate
      }
    };
    auto ldxp = [&](int tt, unsigned short* dst) {
#pragma unroll
      for (int q = 0; q < 4; ++q)
#pragma unroll
        for (int r = 0; r < 4; ++r) {
          int b = btile * 16 + lq * 4 + r;
          dst[q * 4 + r] = xp[((size_t)((dir * Sn + tt) * Bn + b)) * 1536 + q * 384 + hwb + lr];
        }
    };
    unsigned short xcur[16], xnxt[16];
    int t0 = dir ? (Sn - 1) : 0;
    gate(t0);
    ldxp(t0, xcur);

    f32x4 c0 = (f32x4){0.f, 0.f, 0.f, 0.f};
    int skipU = 0;                          // V17: adaptive pre-sleep units (~512cy)

    for (int it = 0; it < Sn; ++it) {
      int t = dir ? (Sn - 1 - it) : it;
      int tn = (it + 1 < Sn) ? (dir ? (Sn - 2 - it) : (it + 1)) : t;
      gate(tn);
      ldxp(tn, xnxt);                       // issued now, consumed at loop end

      f32x4 acc[4];
#pragma unroll
      for (int q = 0; q < 4; ++q) acc[q] = (f32x4){0.f, 0.f, 0.f, 0.f};

      if (it > 0) {
        const unsigned int expT = (unsigned int)it;
        int slot = (it - 1) & 1;
        const unsigned long long* srow = (const unsigned long long*)
            (htag + (size_t)(dir * 2 + slot) * 64 * 384 + (size_t)(btile * 16 + pr) * 384);
        unsigned long long v[12];
        // V17: adaptive pre-sleep — cut speculative poll traffic (~2.7TB/s
        // of useless IC reads at 6 rounds/step). Bounded; spin unchanged.
        for (int z = 0; z < skipU; ++z) __builtin_amdgcn_s_sleep(8);
        int polls = 0;
        while (true) {                      // split-phase spin round (V16)
#pragma unroll
          for (int i = 0; i < 12; ++i)
            v[i] = __hip_atomic_load(&srow[pk + 16 * i],
                                     __ATOMIC_RELAXED, __HIP_MEMORY_SCOPE_AGENT);
          bool ok = true;
#pragma unroll
          for (int i = 0; i < 12; ++i)
            ok &= (((unsigned int)(v[i] >> 16) & 0xffffu) == expT) &
                  ((unsigned int)(v[i] >> 48) == expT);
          ++polls;
          if (__all((int)ok)) break;
          __builtin_amdgcn_s_sleep(1);
        }
        // integrator: converge to ~2 polls/step; negative feedback on overshoot
        if (polls > 2)      { skipU += polls - 2; if (skipU > 16) skipU = 16; }
        else if (polls <= 1){ if (skipU > 0) --skipU; }
        unsigned int* dst = hlds[it & 1];
#pragma unroll
        for (int i = 0; i < 12; ++i)
          dst[pr * 196 + pk + 16 * i] = ((unsigned int)v[i] & 0xffffu) |
                                        (((unsigned int)(v[i] >> 32) & 0xffffu) << 16);
        __syncthreads();                    // the ONLY barrier per step
        const char* src = (const char*)hlds[it & 1];
#pragma unroll
        for (int kf = 0; kf < 12; ++kf) {
          short8 a = *(const short8*)(src + lr * 784 + kf * 64 + lq * 16);
#pragma unroll
          for (int q = 0; q < 4; ++q)
            acc[q] = __builtin_amdgcn_mfma_f32_16x16x32_bf16(a, bfr[q][kf], acc[q], 0, 0, 0);
        }
      }

      // cell (xp folded here) + publish (producer NEVER waits)
      unsigned int outTag = (unsigned int)(it + 1) << 16;
      int oslot = it & 1;
      unsigned int* obase = htag + (size_t)(dir * 2 + oslot) * 64 * 384;
      unsigned short hb16v[4];
#pragma unroll
      for (int r = 0; r < 4; ++r) {
        float iv = sigm(acc[0][r] + bf2f(xcur[0 * 4 + r]));
        float fv = sigm(acc[1][r] + bf2f(xcur[1 * 4 + r]));
        float gv = tanhft(acc[2][r] + bf2f(xcur[2 * 4 + r]));
        float ov = sigm(acc[3][r] + bf2f(xcur[3 * 4 + r]));
        float cf = fv * c0[r] + iv * gv;
        c0[r] = cf;
        float hv = ov * tanhft(cf);
        hb16v[r] = f2bf(hv);
        int b = btile * 16 + lq * 4 + r;
        __hip_atomic_store(&obase[(size_t)b * 384 + hwb + lr],
                           outTag | hb16v[r], __ATOMIC_RELAXED, __HIP_MEMORY_SCOPE_AGENT);
      }
#pragma unroll
      for (int r = 0; r < 4; ++r) {         // h_all row (t*64+b): clobbers only f0p(t)
        int b = btile * 16 + lq * 4 + r;
        f0h[((size_t)(t * Bn + b)) * 768 + dir * Hn + hwb + lr] = hb16v[r];
      }
#pragma unroll
      for (int i = 0; i < 16; ++i) xcur[i] = xnxt[i];
    }
    return;
  }

  // ================= xp GEMM tile =================
  // priority map: early blocks produce mtiles from both t-ends.
  int gb = bid - NRWG;                      // 0..6143
  int q = gb / 48, r = gb % 48;
  int mtile = (r < 24) ? q : (255 - q);     // 256 mtiles (2 t x 64 b each)
  int ntile = r % 24;                       // 24 ntiles
  unsigned short* As = (unsigned short*)smem;
  unsigned short* Bs = (unsigned short*)(smem + 8192);
  int mBase = mtile * 128, nBase = ntile * 128;
  int mw = (w & 1) * 64, nw = (w >> 1) * 64;
  f32x4 acc[4][4];
#pragma unroll
  for (int mt = 0; mt < 4; ++mt)
#pragma unroll
    for (int nt = 0; nt < 4; ++nt) acc[mt][nt] = (f32x4){0.f, 0.f, 0.f, 0.f};

  for (int kb = 0; kb < 24; ++kb) {
    int k0 = kb * 32;
#pragma unroll
    for (int j = 0; j < 2; ++j) {
      int g = j * 256 + tid;
      int row = g >> 2, kc = (g & 3) * 8;
      GLL16(f0h + (size_t)(mBase + row) * 768 + k0 + kc, (char*)As + (j * 256 + w * 64) * 16);
      GLL16(wih + (size_t)(nBase + row) * 768 + k0 + kc, (char*)Bs + (j * 256 + w * 64) * 16);
    }
    __syncthreads();
    short8 af[4], bfv[4];
#pragma unroll
    for (int mt = 0; mt < 4; ++mt) af[mt] = *(const short8*)&As[(mw + mt * 16 + lr) * 32 + lq * 8];
#pragma unroll
    for (int nt = 0; nt < 4; ++nt) bfv[nt] = *(const short8*)&Bs[(nw + nt * 16 + lr) * 32 + lq * 8];
#pragma unroll
    for (int mt = 0; mt < 4; ++mt)
#pragma unroll
      for (int nt = 0; nt < 4; ++nt)
        acc[mt][nt] = __builtin_amdgcn_mfma_f32_16x16x32_bf16(af[mt], bfv[nt], acc[mt][nt], 0, 0, 0);
    __syncthreads();
  }
  // ---- V15 epilogue: LDS stage (+bias) -> full-sector u64 agent stores ----
  unsigned short* stage = (unsigned short*)smem;  // 33.8KB, As/Bs dead
#pragma unroll
  for (int nt = 0; nt < 4; ++nt) {
    int n = nBase + nw + nt * 16 + lr;
    float bias = biasc[n];
#pragma unroll
    for (int mt = 0; mt < 4; ++mt)
#pragma unroll
      for (int rr = 0; rr < 4; ++rr)
        stage[(mw + mt * 16 + lq * 4 + rr) * 132 + nw + nt * 16 + lr] =
            f2bf(acc[mt][nt][rr] + bias);
  }
  __syncthreads();
  {
    int d = (nBase >= 1536) ? 1 : 0;
    int gI0 = nBase - d * 1536;
    int g8 = l >> 3, sub = l & 7;           // 8-lane groups fill 64B sectors
#pragma unroll
    for (int i = 0; i < 16; ++i) {
      int row = w * 32 + (i & 3) * 8 + g8;  // 4 row-octets
      int s = i >> 2;                       // 4 sectors per row (256B)
      int m = mBase + row, t2 = m >> 6, b2 = m & 63;
      unsigned long long val;
      memcpy(&val, &stage[row * 132 + s * 32 + sub * 4], 8);
      unsigned long long* dp = (unsigned long long*)
          (xp + ((size_t)((d * Sn + t2) * Bn + b2)) * 1536 + gI0) + s * 8 + sub;
      __hip_atomic_store(dp, val, __ATOMIC_RELAXED, __HIP_MEMORY_SCOPE_AGENT);
    }
  }
  asm volatile("s_waitcnt vmcnt(0)" ::: "memory");      // all stores at IC
  __syncthreads();                                       // whole wg drained
  if (tid == 0)
    __hip_atomic_fetch_add(&gcnt[mtile >> 3], 1u, __ATOMIC_RELAXED,
                           __HIP_MEMORY_SCOPE_AGENT);
}

// ---------------------------------------------------------------------------
// out GEMM: A = h_all rows [t*64+b][768] bf16, B = wlin [425][768] bf16
// out[(b*S+t)*C + n] fp32 = A@B^T + blin
__global__ void gemm_out(const unsigned short* __restrict__ A, const unsigned short* __restrict__ Bw,
                         const float* __restrict__ blin, float* __restrict__ out) {
  __shared__ __align__(16) unsigned short As[128 * 32];
  __shared__ __align__(16) unsigned short Bs[128 * 32];
  int tid = threadIdx.x, w = tid >> 6, l = tid & 63, lr = l & 15, lq = l >> 4;
  int mBase = blockIdx.x * 128, nBase = blockIdx.y * 128;
  int mw = (w & 1) * 64, nw = (w >> 1) * 64;
  f32x4 acc[4][4];
#pragma unroll
  for (int mt = 0; mt < 4; ++mt)
#pragma unroll
    for (int nt = 0; nt < 4; ++nt) acc[mt][nt] = (f32x4){0.f, 0.f, 0.f, 0.f};

  for (int kb = 0; kb < 24; ++kb) {
    int k0 = kb * 32;
#pragma unroll
    for (int j = 0; j < 2; ++j) {
      int g = j * 256 + tid;
      int row = g >> 2, kc = (g & 3) * 8;
      int nr = nBase + row; if (nr > Cn - 1) nr = Cn - 1;   // clamp: Wlin has 425 rows
      GLL16(A + (size_t)(mBase + row) * 768 + k0 + kc, (char*)As + (j * 256 + w * 64) * 16);
      GLL16(Bw + (size_t)nr * 768 + k0 + kc, (char*)Bs + (j * 256 + w * 64) * 16);
    }
    __syncthreads();
    short8 af[4], bfv[4];
#pragma unroll
    for (int mt = 0; mt < 4; ++mt) af[mt] = *(const short8*)&As[(mw + mt * 16 + lr) * 32 + lq * 8];
#pragma unroll
    for (int nt = 0; nt < 4; ++nt) bfv[nt] = *(const short8*)&Bs[(nw + nt * 16 + lr) * 32 + lq * 8];
#pragma unroll
    for (int mt = 0; mt < 4; ++mt)
#pragma unroll
      for (int nt = 0; nt < 4; ++nt)
        acc[mt][nt] = __builtin_amdgcn_mfma_f32_16x16x32_bf16(af[mt], bfv[nt], acc[mt][nt], 0, 0, 0);
    __syncthreads();
  }
#pragma unroll
  for (int nt = 0; nt < 4; ++nt) {
    int n = nBase + nw + nt * 16 + lr;
    if (n < Cn) {
      float bias = blin[n];
#pragma unroll
      for (int mt = 0; mt < 4; ++mt) {
#pragma unroll
        for (int r = 0; r < 4; ++r) {
          int m = mBase + mw + mt * 16 + lq * 4 + r;
          int t = m >> 6, b = m & 63;       // rows are [t*64+b]
          out[((size_t)(b * Sn + t)) * Cn + n] = acc[mt][nt][r] + bias;
        }
      }
    }
  }
}

// ---------------------------------------------------------------------------
extern "C" void kernel_launch(void* const* d_in, const int* in_sizes, int n_in,
                              void* d_out, int out_size, void* d_ws, size_t ws_size,
                              hipStream_t stream) {
  (void)in_sizes; (void)n_in; (void)out_size;
  const float* f0     = (const float*)d_in[0];
  const int*   counts = (const int*)  d_in[1];
  const float* Wih_f  = (const float*)d_in[2];
  const float* Whh_f  = (const float*)d_in[3];
  const float* bih_f  = (const float*)d_in[4];
  const float* bhh_f  = (const float*)d_in[5];
  const float* Wih_b  = (const float*)d_in[6];
  const float* Whh_b  = (const float*)d_in[7];
  const float* bih_b  = (const float*)d_in[8];
  const float* bhh_b  = (const float*)d_in[9];
  const float* Wlin   = (const float*)d_in[10];
  const float* blin   = (const float*)d_in[11];
  float* out = (float*)d_out;

  char* ws = (char*)d_ws;
  size_t o = 0;
  auto alloc = [&](size_t bytes) { size_t cur = o; o += (bytes + 255) & ~(size_t)255; return cur; };
  size_t o_f0p    = alloc((size_t)Bn * Sn * Dn * 2);        // 50.3 MB (f0p; overlaid h_all)
  size_t o_xp     = alloc((size_t)2 * Sn * Bn * G4H * 2);   // 201.3 MB
  size_t o_wih    = alloc((size_t)3072 * 768 * 2);
  size_t o_whh    = alloc((size_t)2 * 1536 * 384 * 2);
  size_t o_wlin   = alloc((size_t)Cn * 768 * 2);
  size_t o_bias   = alloc((size_t)3072 * 4);
  size_t o_starts = alloc((size_t)Bn * Wn * 4);
  size_t o_htag   = alloc((size_t)2 * 2 * 64 * 384 * 4);    // 384 KB, [dir][slot][b][h]
  size_t o_gcnt   = alloc((size_t)32 * 4);                  // contiguous after htag
  if (o > ws_size) return;  // ~261 MiB of workspace

  unsigned short* f0h   = (unsigned short*)(ws + o_f0p);
  unsigned short* xp    = (unsigned short*)(ws + o_xp);
  unsigned short* wih   = (unsigned short*)(ws + o_wih);
  unsigned short* whh   = (unsigned short*)(ws + o_whh);
  unsigned short* wlin  = (unsigned short*)(ws + o_wlin);
  float*          biasc = (float*)(ws + o_bias);
  int*            starts= (int*)(ws + o_starts);
  unsigned int*   htag  = (unsigned int*)(ws + o_htag);
  unsigned int*   gcnt  = (unsigned int*)(ws + o_gcnt);

  prep_kernel<<<ZB + 64 + CB, 256, 0, stream>>>(htag, counts, starts,
                                                Wih_f, Wih_b, Whh_f, Whh_b, Wlin,
                                                bih_f, bhh_f, bih_b, bhh_b,
                                                wih, whh, wlin, biasc);
  pool_kernel<<<(Bn * Sn * 192) / 256, 256, 0, stream>>>(f0, counts, starts, f0h);
  fused_kernel<<<NRWG + 6144, 256, 0, stream>>>(whh, xp, f0h, wih, biasc, htag, gcnt);
  gemm_out<<<dim3(256, 4), 256, 0, stream>>>(f0h, wlin, blin, out);
}